// Round 1
// baseline (45.590 us; speedup 1.0000x reference)
//
#include <hip/hip_runtime.h>
#include <math.h>

#define NGMAX 128
#define TPB 256

// out layout: [labels(A) | reg(A*8) | dir(A*4)]  (float32)

__device__ __forceinline__ void encode_write(
    const float* __restrict__ anchors, const float (*sgt)[8],
    int a, int bg, int A, float* __restrict__ out)
{
  const float* an = anchors + (size_t)a * 7;
  float xa = an[0], ya = an[1], za = an[2], la = an[3], wa = an[4], ha = an[5], ra = an[6];
  float xg = sgt[bg][0], yg = sgt[bg][1], zg = sgt[bg][2];
  float lg = sgt[bg][3], wg = sgt[bg][4], hg = sgt[bg][5], rg = sgt[bg][6];
  float diag = sqrtf(la * la + wa * wa);
  float r[8];
  r[0] = (xg - xa) / diag;
  r[1] = (yg - ya) / diag;
  r[2] = (zg - za) / ha;
  r[3] = logf(lg / la);
  r[4] = logf(wg / wa);
  r[5] = logf(hg / ha);
  r[6] = cosf(rg) - cosf(ra);
  r[7] = sinf(rg) - sinf(ra);
  const float TWO_PI  = 6.2831854820251465f;  // float32(2*pi)
  const float HALF_PI = 1.5707963705062866f;  // float32(pi/2)
  float m = fmodf(rg, TWO_PI);
  if (m < 0.f) m += TWO_PI;
  int q = (int)floorf(m / HALF_PI);
  q = q < 0 ? 0 : (q > 3 ? 3 : q);
  float* rp = out + (size_t)A + (size_t)a * 8;
  float* dp = out + (size_t)9 * A + (size_t)a * 4;
#pragma unroll
  for (int k = 0; k < 8; ++k) rp[k] = r[k];
#pragma unroll
  for (int k = 0; k < 4; ++k) dp[k] = (k == q) ? 1.f : 0.f;
}

__device__ __forceinline__ void stage_gt(
    const float* __restrict__ gt, int tid, int NG,
    float4* sbox, float* sa2, float (*sgt)[8])
{
  if (tid < NG) {
    const float* g = gt + (size_t)tid * 7;
    float xg = g[0], yg = g[1], zg = g[2], lg = g[3], wg = g[4], hg = g[5], rg = g[6];
    sgt[tid][0] = xg; sgt[tid][1] = yg; sgt[tid][2] = zg; sgt[tid][3] = lg;
    sgt[tid][4] = wg; sgt[tid][5] = hg; sgt[tid][6] = rg;
    float c = fabsf(cosf(rg)), s = fabsf(sinf(rg));
    float ex = 0.5f * (lg * c + wg * s);
    float ey = 0.5f * (lg * s + wg * c);
    float x0 = xg - ex, y0 = yg - ey, x2 = xg + ex, y3 = yg + ey;
    sbox[tid] = make_float4(x0, y0, x2, y3);
    sa2[tid] = (x2 - x0 + 1.f) * (y3 - y0 + 1.f);
  }
}

__global__ void k_init(unsigned long long* __restrict__ top1, int NG)
{
  int t = threadIdx.x;
  // packed (iou=0.0f bits=0) << 32 | (0xFFFFFFFF - anchor 0)
  if (t < NG) top1[t] = 0xFFFFFFFFull;
}

__global__ void __launch_bounds__(TPB) k_main(
    const float* __restrict__ gt, const float* __restrict__ anchors,
    const float* __restrict__ standup, float* __restrict__ out,
    unsigned long long* __restrict__ top1, int A, int NG)
{
  __shared__ float4 sbox[NGMAX];
  __shared__ float  sa2[NGMAX];
  __shared__ float  sgt[NGMAX][8];
  __shared__ int    cand[NGMAX];
  __shared__ int    ncand;
  __shared__ float  slo_x[TPB / 64], slo_y[TPB / 64], shi_x[TPB / 64], shi_y[TPB / 64];

  const int tid = threadIdx.x;
  if (tid == 0) ncand = 0;
  stage_gt(gt, tid, NG, sbox, sa2, sgt);

  const int a = blockIdx.x * TPB + tid;
  const bool valid = (a < A);
  float ax0 = 1e30f, ay0 = 1e30f, ax2 = -1e30f, ay3 = -1e30f;
  if (valid) {
    float4 v = ((const float4*)standup)[a];
    ax0 = v.x; ay0 = v.y; ax2 = v.z; ay3 = v.w;
  }
  const float a1 = (ax2 - ax0 + 1.f) * (ay3 - ay0 + 1.f);

  // exact block bbox over this block's anchors (wave reduce + LDS combine)
  float bx0 = ax0, by0 = ay0, bx2 = ax2, by3 = ay3;
#pragma unroll
  for (int off = 32; off > 0; off >>= 1) {
    bx0 = fminf(bx0, __shfl_xor(bx0, off, 64));
    by0 = fminf(by0, __shfl_xor(by0, off, 64));
    bx2 = fmaxf(bx2, __shfl_xor(bx2, off, 64));
    by3 = fmaxf(by3, __shfl_xor(by3, off, 64));
  }
  if ((tid & 63) == 0) {
    int w = tid >> 6;
    slo_x[w] = bx0; slo_y[w] = by0; shi_x[w] = bx2; shi_y[w] = by3;
  }
  __syncthreads();

  // candidate GT filter (conservative: rounded min/max/sub are monotone)
  if (tid < NG) {
    float fx0 = slo_x[0], fy0 = slo_y[0], fx2 = shi_x[0], fy3 = shi_y[0];
#pragma unroll
    for (int w = 1; w < TPB / 64; ++w) {
      fx0 = fminf(fx0, slo_x[w]); fy0 = fminf(fy0, slo_y[w]);
      fx2 = fmaxf(fx2, shi_x[w]); fy3 = fmaxf(fy3, shi_y[w]);
    }
    float4 b = sbox[tid];
    float xe = fminf(fx2, b.z) - fmaxf(fx0, b.x) + 1.f;
    float ye = fminf(fy3, b.w) - fmaxf(fy0, b.y) + 1.f;
    if (xe > 0.f && ye > 0.f) {
      int i = atomicAdd(&ncand, 1);
      cand[i] = tid;
    }
  }
  __syncthreads();

  const int nc = ncand;
  float best = 0.f;
  int bg = 0;
  for (int c = 0; c < nc; ++c) {
    const int g = cand[c];
    const float4 b = sbox[g];
    float xe = fminf(ax2, b.z) - fmaxf(ax0, b.x) + 1.f;
    float ye = fminf(ay3, b.w) - fmaxf(ay0, b.y) + 1.f;
    bool p = (xe > 0.f) && (ye > 0.f);
    float inter = xe * ye;
    float uni = a1 + sa2[g] - inter;
    float iou = p ? (inter / uni) : 0.f;
    // lexicographic (iou, -g) max == numpy first-index argmax, order-independent
    bool better = (iou > best) || ((iou == best) && (g < bg));
    if (better) { best = iou; bg = g; }
    // per-GT top1: only waves with a positive iou participate
    unsigned long long bal = __ballot(iou > 0.f);
    if (bal) {
      float m = iou;
#pragma unroll
      for (int off = 32; off > 0; off >>= 1)
        m = fmaxf(m, __shfl_xor(m, off, 64));
      if (iou == m) {  // only lanes at the wave max (all have iou>0)
        unsigned long long pk =
            (((unsigned long long)__float_as_uint(m)) << 32) |
            (unsigned long long)(0xFFFFFFFFu - (unsigned)a);
        atomicMax(&top1[g], pk);
      }
    }
  }

  if (valid) {
    const bool posm = best > 0.6f;
    out[a] = posm ? 1.f : ((best < 0.45f) ? 0.f : -1.f);
    float* rp = out + (size_t)A + (size_t)a * 8;
    float* dp = out + (size_t)9 * A + (size_t)a * 4;
    if (posm) {
      encode_write(anchors, sgt, a, bg, A, out);
    } else {
      if ((A & 3) == 0) {
        float4 z = make_float4(0.f, 0.f, 0.f, 0.f);
        ((float4*)rp)[0] = z;
        ((float4*)rp)[1] = z;
        *((float4*)dp) = z;
      } else {
#pragma unroll
        for (int k = 0; k < 8; ++k) rp[k] = 0.f;
#pragma unroll
        for (int k = 0; k < 4; ++k) dp[k] = 0.f;
      }
    }
  }
}

// Fix up the <=128 top1-forced anchors: label=1, recompute reg/dir from the
// anchor's own argmax GT (full 128-GT scan; tiny).
__global__ void k_fix(
    const float* __restrict__ gt, const float* __restrict__ anchors,
    const float* __restrict__ standup, float* __restrict__ out,
    const unsigned long long* __restrict__ top1, int A, int NG)
{
  __shared__ float4 sbox[NGMAX];
  __shared__ float  sa2[NGMAX];
  __shared__ float  sgt[NGMAX][8];
  int tid = threadIdx.x;
  stage_gt(gt, tid, NG, sbox, sa2, sgt);
  __syncthreads();
  if (tid < NG) {
    unsigned long long pk = top1[tid];
    unsigned a = 0xFFFFFFFFu - (unsigned)(pk & 0xFFFFFFFFull);
    if (a < (unsigned)A) {
      float4 v = ((const float4*)standup)[a];
      float a1 = (v.z - v.x + 1.f) * (v.w - v.y + 1.f);
      float best = 0.f;
      int bg = 0;
      for (int g = 0; g < NG; ++g) {
        float4 b = sbox[g];
        float xe = fminf(v.z, b.z) - fmaxf(v.x, b.x) + 1.f;
        float ye = fminf(v.w, b.w) - fmaxf(v.y, b.y) + 1.f;
        bool p = (xe > 0.f) && (ye > 0.f);
        float inter = xe * ye;
        float uni = a1 + sa2[g] - inter;
        float iou = p ? (inter / uni) : 0.f;
        if (iou > best || (iou == best && g < bg)) { best = iou; bg = g; }
      }
      out[a] = 1.f;  // pos via is_top1 (idempotent across duplicate winners)
      encode_write(anchors, sgt, (int)a, bg, A, out);
    }
  }
}

extern "C" void kernel_launch(void* const* d_in, const int* in_sizes, int n_in,
                              void* d_out, int out_size, void* d_ws, size_t ws_size,
                              hipStream_t stream)
{
  const float* gt      = (const float*)d_in[0];
  const float* anchors = (const float*)d_in[1];
  const float* standup = (const float*)d_in[2];
  float* out = (float*)d_out;
  const int NG = in_sizes[0] / 7;           // 128
  const int A  = in_sizes[2] / 4;           // ~281600
  unsigned long long* top1 = (unsigned long long*)d_ws;  // NG * 8 bytes

  hipLaunchKernelGGL(k_init, dim3(1), dim3(NGMAX), 0, stream, top1, NG);
  hipLaunchKernelGGL(k_main, dim3((A + TPB - 1) / TPB), dim3(TPB), 0, stream,
                     gt, anchors, standup, out, top1, A, NG);
  hipLaunchKernelGGL(k_fix, dim3(1), dim3(NGMAX), 0, stream,
                     gt, anchors, standup, out, top1, A, NG);
}

// Round 2
// 17.858 us; speedup vs baseline: 2.5528x; 2.5528x over previous
//
#include <hip/hip_runtime.h>
#include <math.h>

#define NGMAX 128
#define TPB 256
#define NX 704          // x cells: (140.8-(-140.8))/0.4
#define NYA 200         // y cells: (40-(-40))/0.4
#define ND 2
#define X0C (-140.6f)   // first anchor center x
#define Y0C (-39.8f)    // first anchor center y
#define PADW 3.0f       // max anchor extent (1.96) + 1.0 iou slop + margin

// out layout: [labels(A) | reg(A*8) | dir(A*4)]  (float32)

__device__ __forceinline__ void encode_write(
    const float* __restrict__ anchors, const float (*sgt)[8],
    int a, int bg, int A, float* __restrict__ out)
{
  const float* an = anchors + (size_t)a * 7;
  float xa = an[0], ya = an[1], za = an[2], la = an[3], wa = an[4], ha = an[5], ra = an[6];
  float xg = sgt[bg][0], yg = sgt[bg][1], zg = sgt[bg][2];
  float lg = sgt[bg][3], wg = sgt[bg][4], hg = sgt[bg][5], rg = sgt[bg][6];
  float diag = sqrtf(la * la + wa * wa);
  float r[8];
  r[0] = (xg - xa) / diag;
  r[1] = (yg - ya) / diag;
  r[2] = (zg - za) / ha;
  r[3] = logf(lg / la);
  r[4] = logf(wg / wa);
  r[5] = logf(hg / ha);
  r[6] = cosf(rg) - cosf(ra);
  r[7] = sinf(rg) - sinf(ra);
  const float TWO_PI  = 6.2831854820251465f;
  const float HALF_PI = 1.5707963705062866f;
  float m = fmodf(rg, TWO_PI);
  if (m < 0.f) m += TWO_PI;
  int q = (int)floorf(m / HALF_PI);
  q = q < 0 ? 0 : (q > 3 ? 3 : q);
  float* rp = out + (size_t)A + (size_t)a * 8;
  float* dp = out + (size_t)9 * A + (size_t)a * 4;
#pragma unroll
  for (int k = 0; k < 8; ++k) rp[k] = r[k];
#pragma unroll
  for (int k = 0; k < 4; ++k) dp[k] = (k == q) ? 1.f : 0.f;
}

// ---------------- K1: per-GT top1 anchor (argmax of the GT's iou column) ---
// Scans only the GT's positive-iou window of the regular anchor grid.
// No atomics, no init: plain store of top1A[g].
__global__ void __launch_bounds__(TPB) k_top1(
    const float* __restrict__ gt, const float* __restrict__ standup,
    int* __restrict__ top1A, int A, int NG)
{
  const int g = blockIdx.x;
  if (g >= NG) return;
  const float* gp = gt + (size_t)g * 7;
  float xg = gp[0], yg = gp[1], lg = gp[3], wg = gp[4], rg = gp[6];
  float c = fabsf(cosf(rg)), s = fabsf(sinf(rg));
  float ex = 0.5f * (lg * c + wg * s);
  float ey = 0.5f * (lg * s + wg * c);
  float bx0 = xg - ex, by0 = yg - ey, bx2 = xg + ex, by3 = yg + ey;
  float a2 = (bx2 - bx0 + 1.f) * (by3 - by0 + 1.f);

  // conservative window (any anchor with iou>0 has center within +-(ext+1))
  int i_lo = (int)floorf((bx0 - PADW - X0C) * 2.5f) - 1;
  int i_hi = (int)ceilf ((bx2 + PADW - X0C) * 2.5f) + 1;
  int j_lo = (int)floorf((by0 - PADW - Y0C) * 2.5f) - 1;
  int j_hi = (int)ceilf ((by3 + PADW - Y0C) * 2.5f) + 1;
  i_lo = i_lo < 0 ? 0 : i_lo;  i_hi = i_hi > NX - 1 ? NX - 1 : i_hi;
  j_lo = j_lo < 0 ? 0 : j_lo;  j_hi = j_hi > NYA - 1 ? NYA - 1 : j_hi;

  const int nyw = j_hi - j_lo + 1;
  const int total = (i_hi - i_lo + 1) * nyw * ND;

  unsigned long long pk = 0;  // (iou_bits<<32) | (~anchor): lexicographic max
  for (int t = threadIdx.x; t < total; t += TPB) {
    int d = t & 1;
    int q = t >> 1;
    int jj = q % nyw, ii = q / nyw;
    int a = ((i_lo + ii) * NYA + (j_lo + jj)) * ND + d;
    float4 v = ((const float4*)standup)[a];
    float a1 = (v.z - v.x + 1.f) * (v.w - v.y + 1.f);
    float xe = fminf(v.z, bx2) - fmaxf(v.x, bx0) + 1.f;
    float ye = fminf(v.w, by3) - fmaxf(v.y, by0) + 1.f;
    if (xe > 0.f && ye > 0.f) {
      float inter = xe * ye;
      float iou = inter / (a1 + a2 - inter);
      unsigned long long p =
          (((unsigned long long)__float_as_uint(iou)) << 32) |
          (unsigned long long)(0xFFFFFFFFu - (unsigned)a);
      pk = pk > p ? pk : p;
    }
  }
#pragma unroll
  for (int off = 32; off > 0; off >>= 1) {
    unsigned long long o = __shfl_xor(pk, off, 64);
    pk = pk > o ? pk : o;
  }
  __shared__ unsigned long long spk[TPB / 64];
  if ((threadIdx.x & 63) == 0) spk[threadIdx.x >> 6] = pk;
  __syncthreads();
  if (threadIdx.x == 0) {
#pragma unroll
    for (int w = 1; w < TPB / 64; ++w) pk = pk > spk[w] ? pk : spk[w];
    // empty column (no positive iou) -> argmax over zeros = anchor 0
    int a = (pk >> 32) ? (int)(0xFFFFFFFFu - (unsigned)(pk & 0xFFFFFFFFull)) : 0;
    top1A[g] = a;
  }
}

// ---------------- K2: per-anchor labels / reg / dir ------------------------
__global__ void __launch_bounds__(TPB) k_main(
    const float* __restrict__ gt, const float* __restrict__ anchors,
    const float* __restrict__ standup, float* __restrict__ out,
    const int* __restrict__ top1A, int A, int NG)
{
  __shared__ float4 sbox[NGMAX];
  __shared__ float  sa2[NGMAX];
  __shared__ float  sgt[NGMAX][8];
  __shared__ int    cand[NGMAX];
  __shared__ int    stop1[NGMAX];
  __shared__ int    ncand;
  __shared__ float  slo_x[TPB / 64], slo_y[TPB / 64], shi_x[TPB / 64], shi_y[TPB / 64];

  const int tid = threadIdx.x;
  if (tid == 0) ncand = 0;
  if (tid < NG) {
    const float* g = gt + (size_t)tid * 7;
    float xg = g[0], yg = g[1], zg = g[2], lg = g[3], wg = g[4], hg = g[5], rg = g[6];
    sgt[tid][0] = xg; sgt[tid][1] = yg; sgt[tid][2] = zg; sgt[tid][3] = lg;
    sgt[tid][4] = wg; sgt[tid][5] = hg; sgt[tid][6] = rg;
    float c = fabsf(cosf(rg)), s = fabsf(sinf(rg));
    float ex = 0.5f * (lg * c + wg * s);
    float ey = 0.5f * (lg * s + wg * c);
    float x0 = xg - ex, y0 = yg - ey, x2 = xg + ex, y3 = yg + ey;
    sbox[tid] = make_float4(x0, y0, x2, y3);
    sa2[tid] = (x2 - x0 + 1.f) * (y3 - y0 + 1.f);
  }

  const int a = blockIdx.x * TPB + tid;
  const bool valid = (a < A);
  float ax0 = 1e30f, ay0 = 1e30f, ax2 = -1e30f, ay3 = -1e30f;
  if (valid) {
    float4 v = ((const float4*)standup)[a];
    ax0 = v.x; ay0 = v.y; ax2 = v.z; ay3 = v.w;
  }
  const float a1 = (ax2 - ax0 + 1.f) * (ay3 - ay0 + 1.f);

  // exact block bbox (wave shuffle reduce + LDS combine)
  float bx0 = ax0, by0 = ay0, bx2 = ax2, by3 = ay3;
#pragma unroll
  for (int off = 32; off > 0; off >>= 1) {
    bx0 = fminf(bx0, __shfl_xor(bx0, off, 64));
    by0 = fminf(by0, __shfl_xor(by0, off, 64));
    bx2 = fmaxf(bx2, __shfl_xor(bx2, off, 64));
    by3 = fmaxf(by3, __shfl_xor(by3, off, 64));
  }
  if ((tid & 63) == 0) {
    int w = tid >> 6;
    slo_x[w] = bx0; slo_y[w] = by0; shi_x[w] = bx2; shi_y[w] = by3;
  }
  __syncthreads();

  // candidate GT filter (monotone-float conservative superset of iou>0)
  if (tid < NG) {
    float fx0 = slo_x[0], fy0 = slo_y[0], fx2 = shi_x[0], fy3 = shi_y[0];
#pragma unroll
    for (int w = 1; w < TPB / 64; ++w) {
      fx0 = fminf(fx0, slo_x[w]); fy0 = fminf(fy0, slo_y[w]);
      fx2 = fmaxf(fx2, shi_x[w]); fy3 = fmaxf(fy3, shi_y[w]);
    }
    float4 b = sbox[tid];
    float xe = fminf(fx2, b.z) - fmaxf(fx0, b.x) + 1.f;
    float ye = fminf(fy3, b.w) - fmaxf(fy0, b.y) + 1.f;
    if (xe > 0.f && ye > 0.f) {
      int i = atomicAdd(&ncand, 1);
      cand[i]  = tid;
      stop1[i] = top1A[tid];
    }
  }
  __syncthreads();

  const int nc = ncand;
  float best = 0.f;
  int bg = 0;
  bool forced = false;
  for (int c = 0; c < nc; ++c) {
    const int g = cand[c];
    const float4 b = sbox[g];
    float xe = fminf(ax2, b.z) - fmaxf(ax0, b.x) + 1.f;
    float ye = fminf(ay3, b.w) - fmaxf(ay0, b.y) + 1.f;
    bool p = (xe > 0.f) && (ye > 0.f);
    float inter = xe * ye;
    float uni = a1 + sa2[g] - inter;
    float iou = p ? (inter / uni) : 0.f;
    // lexicographic (iou, -g) max == numpy first-index argmax
    bool better = (iou > best) || ((iou == best) && (g < bg));
    if (better) { best = iou; bg = g; }
    forced |= (stop1[c] == a);
  }

  if (valid) {
    const bool posm = (best > 0.6f) || forced;
    out[a] = posm ? 1.f : ((best < 0.45f) ? 0.f : -1.f);
    float* rp = out + (size_t)A + (size_t)a * 8;
    float* dp = out + (size_t)9 * A + (size_t)a * 4;
    if (posm) {
      encode_write(anchors, sgt, a, bg, A, out);
    } else {
      if ((A & 3) == 0) {
        float4 z = make_float4(0.f, 0.f, 0.f, 0.f);
        ((float4*)rp)[0] = z;
        ((float4*)rp)[1] = z;
        *((float4*)dp) = z;
      } else {
#pragma unroll
        for (int k = 0; k < 8; ++k) rp[k] = 0.f;
#pragma unroll
        for (int k = 0; k < 4; ++k) dp[k] = 0.f;
      }
    }
  }
}

extern "C" void kernel_launch(void* const* d_in, const int* in_sizes, int n_in,
                              void* d_out, int out_size, void* d_ws, size_t ws_size,
                              hipStream_t stream)
{
  const float* gt      = (const float*)d_in[0];
  const float* anchors = (const float*)d_in[1];
  const float* standup = (const float*)d_in[2];
  float* out = (float*)d_out;
  const int NG = in_sizes[0] / 7;   // 128
  const int A  = in_sizes[2] / 4;   // 281600
  int* top1A = (int*)d_ws;          // NG ints, written by k_top1 every call

  hipLaunchKernelGGL(k_top1, dim3(NG), dim3(TPB), 0, stream,
                     gt, standup, top1A, A, NG);
  hipLaunchKernelGGL(k_main, dim3((A + TPB - 1) / TPB), dim3(TPB), 0, stream,
                     gt, anchors, standup, out, top1A, A, NG);
}